// Round 6
// baseline (42.050 us; speedup 1.0000x reference)
//
#include <hip/hip_runtime.h>

// DynamicMaskHead v6: all-MFMA, 16-px waves, full-occupancy.
// Wave = one 16-px tile x all instances of its image. 5 MFMA per instance:
//   acc0 = ca·coords + W0a·X + W0b·X   (coords/b0 as hi/lo bf16 channels)
//   h0 = relu -> a1b MFMA (b1 bias channel) -> h1 = relu -> a2r MFMA
// a2r is row-replicated w2 => all D rows equal => lane group g banks
// instance (m&3)==g, one 64-lane coalesced store per 4 instances.
// K-consistency fragment trick + C/D layout verified rounds 2-5
// (absmax 0.047). VGPR budget <= 64 -> 8 waves/SIMD.

#define CIN  64
#define HH   160
#define WW   256
#define HWSZ (HH * WW)
#define PP   1361
#define MASK_BIAS_SHIFT 2.19f
#define PKF  1344              // floats per instance in packed buffer (5376 B)

typedef short short8 __attribute__((ext_vector_type(8)));
typedef float f32x4  __attribute__((ext_vector_type(4)));

union BF8 { short8 s; __bf16 b[8]; };

__device__ inline __bf16 bhi(float v) { return (__bf16)v; }
__device__ inline __bf16 blo(float v) { return (__bf16)(v - (float)(__bf16)v); }

// packed float offsets per instance:
//   0: a00 (W0 x-ch 0..31)   256: a01 (x-ch 32..63)   512: a1b (W1 + b1 ch)
//   768: a2r (replicated w2) 1024: ca (coord/b0 ch)   1280: b2 (scalar)

__global__ __launch_bounds__(64) void prep_params(
    const float* __restrict__ params, float* __restrict__ pk)
{
    const int t    = blockIdx.x;
    const int lane = threadIdx.x;
    const int col  = lane & 15;
    const int g    = lane >> 4;
    const float* pw = params + (size_t)t * PP;
    float* dst = pk + (size_t)t * PKF;

    const __bf16 z = (__bf16)0.f;

    BF8 a00, a01;
#pragma unroll
    for (int j = 0; j < 8; ++j) {
        a00.b[j] = (__bf16)pw[col * 66 + 2 +      g * 8 + j];
        a01.b[j] = (__bf16)pw[col * 66 + 2 + 32 + g * 8 + j];
    }

    BF8 a1b;                                   // W1 (k=0..15) + b1 bias channel
#pragma unroll
    for (int j = 0; j < 4; ++j)
        a1b.b[j] = (__bf16)pw[1056 + col * 16 + g * 4 + j];
    {
        const float b1 = pw[1344 + col];
        a1b.b[4] = (g == 0) ? bhi(b1) : z;
        a1b.b[5] = (g == 0) ? blo(b1) : z;
        a1b.b[6] = z;  a1b.b[7] = z;
    }

    BF8 a2r;                                   // w2 replicated across rows
#pragma unroll
    for (int j = 0; j < 4; ++j) a2r.b[j] = (__bf16)pw[1312 + g * 4 + j];
    a2r.b[4] = z; a2r.b[5] = z; a2r.b[6] = z; a2r.b[7] = z;

    BF8 ca;   // [wx_hi,wx_lo,wy_hi,wy_lo,b0_hi,b0_lo,0,0] on g==0 lanes
    {
        const float wx = pw[col * 66 + 0];
        const float wy = pw[col * 66 + 1];
        const float b0 = pw[1328 + col];
        ca.b[0] = (g == 0) ? bhi(wx) : z;
        ca.b[1] = (g == 0) ? blo(wx) : z;
        ca.b[2] = (g == 0) ? bhi(wy) : z;
        ca.b[3] = (g == 0) ? blo(wy) : z;
        ca.b[4] = (g == 0) ? bhi(b0) : z;
        ca.b[5] = (g == 0) ? blo(b0) : z;
        ca.b[6] = z; ca.b[7] = z;
    }

    ((short8*)(dst       ))[lane] = a00.s;
    ((short8*)(dst +  256))[lane] = a01.s;
    ((short8*)(dst +  512))[lane] = a1b.s;
    ((short8*)(dst +  768))[lane] = a2r.s;
    ((short8*)(dst + 1024))[lane] = ca.s;
    if (lane == 0) dst[1280] = pw[1360] - MASK_BIAS_SHIFT;
}

__global__ __launch_bounds__(256, 8) void mask_head_v6(
    const float* __restrict__ x,
    const float* __restrict__ pk,
    const int*   __restrict__ num_ins,
    float*       __restrict__ out,
    int N, int T)
{
    const int tid  = threadIdx.x;
    const int wave = tid >> 6;
    const int lane = tid & 63;
    const int col  = lane & 15;
    const int g    = lane >> 4;
    const int n    = blockIdx.y;
    const int pxt  = blockIdx.x * 64 + wave * 16;   // this wave's 16-px tile

    // instance range for this image (repeat-pad on last image)
    int t0 = 0;
    for (int j = 0; j < n; ++j) t0 += num_ins[j];
    int t1 = t0 + num_ins[n];
    if (n == N - 1) t1 = T;
    if (t1 > T) t1 = T;
    t0 = __builtin_amdgcn_readfirstlane(t0);
    t1 = __builtin_amdgcn_readfirstlane(t1);
    const int M = t1 - t0;

    // x fragments for this tile: 16 px x 64 ch (8 VGPRs)
    BF8 xb0, xb1;
    const float* xbase = x + (size_t)n * CIN * HWSZ + pxt + col;
#pragma unroll
    for (int j = 0; j < 8; ++j) {
        xb0.b[j] = (__bf16)xbase[(size_t)(     g * 8 + j) * HWSZ];
        xb1.b[j] = (__bf16)xbase[(size_t)(32 + g * 8 + j) * HWSZ];
    }

    // coordinate B-fragment (instance-independent): [xf,xf,yf,yf,1,1,0,0]
    BF8 b2c;
    {
        const int px = pxt + col;
        const __bf16 xfb = (__bf16)(float)(px & (WW - 1));
        const __bf16 yfb = (__bf16)(float)(px >> 8);
        b2c.b[0] = xfb; b2c.b[1] = xfb;
        b2c.b[2] = yfb; b2c.b[3] = yfb;
        b2c.b[4] = (__bf16)1.f; b2c.b[5] = (__bf16)1.f;
        b2c.b[6] = (__bf16)0.f; b2c.b[7] = (__bf16)0.f;
    }

    const __bf16 one = (__bf16)1.f, zero = (__bf16)0.f;
    float* const obase = out + pxt + col;

    float oval = 0.f;
#pragma unroll 4
    for (int m = 0; m < M; ++m) {
        const int t = t0 + m;
        const float* pt = pk + (size_t)t * PKF;

        short8 a00 = ((const short8*)(pt       ))[lane];
        short8 a01 = ((const short8*)(pt +  256))[lane];
        short8 a1b = ((const short8*)(pt +  512))[lane];
        short8 a2r = ((const short8*)(pt +  768))[lane];
        short8 ca  = ((const short8*)(pt + 1024))[lane];
        const float b2v = pt[1280];

        // layer 0: coords/b0 + x-channels in one fp32 accumulator
        f32x4 acc0 = {0.f, 0.f, 0.f, 0.f};
        acc0 = __builtin_amdgcn_mfma_f32_16x16x32_bf16(ca,  b2c.s, acc0, 0, 0, 0);
        acc0 = __builtin_amdgcn_mfma_f32_16x16x32_bf16(a00, xb0.s, acc0, 0, 0, 0);
        acc0 = __builtin_amdgcn_mfma_f32_16x16x32_bf16(a01, xb1.s, acc0, 0, 0, 0);

        BF8 h0;
#pragma unroll
        for (int j = 0; j < 4; ++j) h0.b[j] = (__bf16)fmaxf(acc0[j], 0.f);
        h0.b[4] = one; h0.b[5] = one; h0.b[6] = zero; h0.b[7] = zero;

        // layer 1 (b1 via bias channel)
        f32x4 acc1 = {0.f, 0.f, 0.f, 0.f};
        acc1 = __builtin_amdgcn_mfma_f32_16x16x32_bf16(a1b, h0.s, acc1, 0, 0, 0);

        BF8 h1;
#pragma unroll
        for (int j = 0; j < 4; ++j) h1.b[j] = (__bf16)fmaxf(acc1[j], 0.f);
        h1.b[4] = zero; h1.b[5] = zero; h1.b[6] = zero; h1.b[7] = zero;

        // layer 2: row-replicated w2 -> every lane holds the tile's answer
        f32x4 acc2 = {0.f, 0.f, 0.f, 0.f};
        acc2 = __builtin_amdgcn_mfma_f32_16x16x32_bf16(a2r, h1.s, acc2, 0, 0, 0);

        const float res = acc2[0] + b2v;
        if ((m & 3) == g) oval = res;        // lane group banks its instance
        if ((m & 3) == 3)                    // 4 instances x 16 px, 64 lanes
            obase[(size_t)(t - 3 + g) * HWSZ] = oval;
    }
    // tail: M % 4 leftover instances live in groups 0..rem-1
    const int rem = M & 3;
    if (rem && g < rem)
        obase[(size_t)(t1 - rem + g) * HWSZ] = oval;
}

// ---- fallback (no workspace): round-2-style kernel, params from global
__global__ __launch_bounds__(256) void mask_head_mfma_nows(
    const float* __restrict__ x,
    const float* __restrict__ params,
    const int*   __restrict__ num_ins,
    float*       __restrict__ out,
    int N, int T)
{
    const int tid  = threadIdx.x;
    const int wave = tid >> 6;
    const int lane = tid & 63;
    const int col  = lane & 15;
    const int g    = lane >> 4;
    const int n    = blockIdx.y;
    const int pxw  = blockIdx.x * 256 + wave * 64;

    int t0 = 0;
    for (int j = 0; j < n; ++j) t0 += num_ins[j];
    int t1 = t0 + num_ins[n];
    if (n == N - 1) t1 = T;
    if (t1 > T) t1 = T;

    BF8 xb[4][2];
    const float* xbase = x + (size_t)n * CIN * HWSZ + pxw + col;
#pragma unroll
    for (int nt = 0; nt < 4; ++nt)
#pragma unroll
        for (int c = 0; c < 2; ++c)
#pragma unroll
            for (int j = 0; j < 8; ++j)
                xb[nt][c].b[j] = (__bf16)xbase[(size_t)(c * 32 + g * 8 + j) * HWSZ + nt * 16];

    float xf[4], yf[4];
#pragma unroll
    for (int nt = 0; nt < 4; ++nt) {
        const int pix = pxw + nt * 16 + col;
        xf[nt] = (float)(pix & (WW - 1));
        yf[nt] = (float)(pix >> 8);
    }

    for (int t = t0; t < t1; ++t) {
        const float* pw = params + (size_t)t * PP;
        BF8 a00, a01, a1;
#pragma unroll
        for (int j = 0; j < 8; ++j) {
            a00.b[j] = (__bf16)pw[col * 66 + 2 +      g * 8 + j];
            a01.b[j] = (__bf16)pw[col * 66 + 2 + 32 + g * 8 + j];
        }
#pragma unroll
        for (int j = 0; j < 4; ++j) {
            a1.b[j]     = (__bf16)pw[1056 + col * 16 + g * 4 + j];
            a1.b[4 + j] = (__bf16)0.f;
        }
        float wxv[4], wyv[4], b0v[4], b1v[4], w2v[4];
#pragma unroll
        for (int j = 0; j < 4; ++j) {
            const int r = g * 4 + j;
            wxv[j] = pw[r * 66 + 0];
            wyv[j] = pw[r * 66 + 1];
            b0v[j] = pw[1328 + r];
            b1v[j] = pw[1344 + r];
            w2v[j] = pw[1312 + r];
        }
        const float b2v = pw[1360] - MASK_BIAS_SHIFT;

        f32x4 acc0[4];
#pragma unroll
        for (int nt = 0; nt < 4; ++nt) {
            f32x4 a = {0.f, 0.f, 0.f, 0.f};
            a = __builtin_amdgcn_mfma_f32_16x16x32_bf16(a00.s, xb[nt][0].s, a, 0, 0, 0);
            a = __builtin_amdgcn_mfma_f32_16x16x32_bf16(a01.s, xb[nt][1].s, a, 0, 0, 0);
            acc0[nt] = a;
        }
        BF8 h0[4];
#pragma unroll
        for (int nt = 0; nt < 4; ++nt)
#pragma unroll
            for (int j = 0; j < 4; ++j) {
                float v = acc0[nt][j] + b0v[j];
                v = fmaf(wxv[j], xf[nt], v);
                v = fmaf(wyv[j], yf[nt], v);
                v = fmaxf(v, 0.f);
                h0[nt].b[j]     = (__bf16)v;
                h0[nt].b[4 + j] = (__bf16)0.f;
            }
        f32x4 acc1[4];
#pragma unroll
        for (int nt = 0; nt < 4; ++nt) {
            f32x4 a = {0.f, 0.f, 0.f, 0.f};
            acc1[nt] = __builtin_amdgcn_mfma_f32_16x16x32_bf16(a1.s, h0[nt].s, a, 0, 0, 0);
        }
        float oval = 0.f;
#pragma unroll
        for (int nt = 0; nt < 4; ++nt) {
            float sum = 0.f;
#pragma unroll
            for (int j = 0; j < 4; ++j) {
                const float h = fmaxf(acc1[nt][j] + b1v[j], 0.f);
                sum = fmaf(w2v[j], h, sum);
            }
            sum += __shfl_xor(sum, 16, 64);
            sum += __shfl_xor(sum, 32, 64);
            if (nt == g) oval = sum + b2v;
        }
        out[(size_t)t * HWSZ + pxw + lane] = oval;
    }
}

extern "C" void kernel_launch(void* const* d_in, const int* in_sizes, int n_in,
                              void* d_out, int out_size, void* d_ws, size_t ws_size,
                              hipStream_t stream) {
    const float* x      = (const float*)d_in[0];
    const float* params = (const float*)d_in[1];
    const int*   nins   = (const int*)d_in[2];
    float*       out    = (float*)d_out;

    const int N = in_sizes[2];            // images
    const int T = in_sizes[1] / PP;       // total instances (param rows)
    const size_t ws_needed = (size_t)T * PKF * sizeof(float);

    if (ws_size >= ws_needed) {
        float* pk = (float*)d_ws;
        prep_params<<<T, dim3(64), 0, stream>>>(params, pk);
        dim3 grid(HWSZ / 64, N, 1);       // 640 x 4 = 2560 blocks of 4 waves
        mask_head_v6<<<grid, dim3(256), 0, stream>>>(x, pk, nins, out, N, T);
    } else {
        dim3 grid(HWSZ / 256, N);
        mask_head_mfma_nows<<<grid, dim3(256), 0, stream>>>(x, params, nins, out, N, T);
    }
}

// Round 7
// 32.669 us; speedup vs baseline: 1.2872x; 1.2872x over previous
//
#include <hip/hip_runtime.h>

// DynamicMaskHead v7: all-MFMA + LDS double-buffered param staging.
// Block = 4 waves x 64 px = 256 px; all waves loop ALL instances of the
// image together. Per instance: params (5376B packed) staged once per block
// into LDS (double-buffered, loads issued before compute -> latency hidden),
// then 5 ds_read_b128 per wave + 5 MFMA per 16-px tile:
//   acc0 = ca·coords + W0a·X + W0b·X ; h0=relu -> a1b MFMA (b1 channel)
//   -> h1=relu -> a2r MFMA (row-replicated w2) => lane keeps tile nt==g,
//   one 64-lane coalesced store per instance. Zero shuffles.
// Math identical to rounds 5-6 (verified absmax 0.047).

#define CIN  64
#define HH   160
#define WW   256
#define HWSZ (HH * WW)
#define PP   1361
#define MASK_BIAS_SHIFT 2.19f
#define PKF  1344              // floats per instance in packed buffer (5376 B)

typedef short short8 __attribute__((ext_vector_type(8)));
typedef float f32x4  __attribute__((ext_vector_type(4)));

union BF8 { short8 s; __bf16 b[8]; };

__device__ inline __bf16 bhi(float v) { return (__bf16)v; }
__device__ inline __bf16 blo(float v) { return (__bf16)(v - (float)(__bf16)v); }

// packed float offsets per instance:
//   0: a00 (W0 x-ch 0..31)   256: a01 (x-ch 32..63)   512: a1b (W1 + b1 ch)
//   768: a2r (replicated w2) 1024: ca (coord/b0 ch)   1280: b2 (scalar)

__global__ __launch_bounds__(64) void prep_params(
    const float* __restrict__ params, float* __restrict__ pk)
{
    const int t    = blockIdx.x;
    const int lane = threadIdx.x;
    const int col  = lane & 15;
    const int g    = lane >> 4;
    const float* pw = params + (size_t)t * PP;
    float* dst = pk + (size_t)t * PKF;

    const __bf16 z = (__bf16)0.f;

    BF8 a00, a01;
#pragma unroll
    for (int j = 0; j < 8; ++j) {
        a00.b[j] = (__bf16)pw[col * 66 + 2 +      g * 8 + j];
        a01.b[j] = (__bf16)pw[col * 66 + 2 + 32 + g * 8 + j];
    }

    BF8 a1b;                                   // W1 (k=0..15) + b1 bias channel
#pragma unroll
    for (int j = 0; j < 4; ++j)
        a1b.b[j] = (__bf16)pw[1056 + col * 16 + g * 4 + j];
    {
        const float b1 = pw[1344 + col];
        a1b.b[4] = (g == 0) ? bhi(b1) : z;
        a1b.b[5] = (g == 0) ? blo(b1) : z;
        a1b.b[6] = z;  a1b.b[7] = z;
    }

    BF8 a2r;                                   // w2 replicated across rows
#pragma unroll
    for (int j = 0; j < 4; ++j) a2r.b[j] = (__bf16)pw[1312 + g * 4 + j];
    a2r.b[4] = z; a2r.b[5] = z; a2r.b[6] = z; a2r.b[7] = z;

    BF8 ca;   // [wx_hi,wx_lo,wy_hi,wy_lo,b0_hi,b0_lo,0,0] on g==0 lanes
    {
        const float wx = pw[col * 66 + 0];
        const float wy = pw[col * 66 + 1];
        const float b0 = pw[1328 + col];
        ca.b[0] = (g == 0) ? bhi(wx) : z;
        ca.b[1] = (g == 0) ? blo(wx) : z;
        ca.b[2] = (g == 0) ? bhi(wy) : z;
        ca.b[3] = (g == 0) ? blo(wy) : z;
        ca.b[4] = (g == 0) ? bhi(b0) : z;
        ca.b[5] = (g == 0) ? blo(b0) : z;
        ca.b[6] = z; ca.b[7] = z;
    }

    ((short8*)(dst       ))[lane] = a00.s;
    ((short8*)(dst +  256))[lane] = a01.s;
    ((short8*)(dst +  512))[lane] = a1b.s;
    ((short8*)(dst +  768))[lane] = a2r.s;
    ((short8*)(dst + 1024))[lane] = ca.s;
    if (lane == 0) dst[1280] = pw[1360] - MASK_BIAS_SHIFT;
}

__global__ __launch_bounds__(256, 4) void mask_head_v7(
    const float* __restrict__ x,
    const float* __restrict__ pk,
    const int*   __restrict__ num_ins,
    float*       __restrict__ out,
    int N, int T)
{
    __shared__ __align__(16) float plds[2][PKF];   // double-buffered params

    const int tid  = threadIdx.x;
    const int wave = tid >> 6;
    const int lane = tid & 63;
    const int col  = lane & 15;
    const int g    = lane >> 4;
    const int n    = blockIdx.y;
    const int pxw  = blockIdx.x * 256 + wave * 64;

    // instance range for this image (repeat-pad on last image)
    int t0 = 0;
    for (int j = 0; j < n; ++j) t0 += num_ins[j];
    int t1 = t0 + num_ins[n];
    if (n == N - 1) t1 = T;
    if (t1 > T) t1 = T;
    t0 = __builtin_amdgcn_readfirstlane(t0);
    t1 = __builtin_amdgcn_readfirstlane(t1);
    const int M = t1 - t0;
    if (M <= 0) return;

    // x fragments: 64 px x 64 ch (32 VGPR), loaded once, reused by all inst
    BF8 xb[4][2];
    const float* xbase = x + (size_t)n * CIN * HWSZ + pxw + col;
#pragma unroll
    for (int nt = 0; nt < 4; ++nt)
#pragma unroll
        for (int c = 0; c < 2; ++c)
#pragma unroll
            for (int j = 0; j < 8; ++j) {
                const int ch = c * 32 + g * 8 + j;
                xb[nt][c].b[j] = (__bf16)xbase[(size_t)ch * HWSZ + nt * 16];
            }

    // coordinate B-fragments (instance-independent): [xf,xf,yf,yf,1,1,0,0]
    BF8 b2c[4];
#pragma unroll
    for (int nt = 0; nt < 4; ++nt) {
        const int px = pxw + nt * 16 + col;
        const __bf16 xfb = (__bf16)(float)(px & (WW - 1));
        const __bf16 yfb = (__bf16)(float)(px >> 8);
        b2c[nt].b[0] = xfb; b2c[nt].b[1] = xfb;
        b2c[nt].b[2] = yfb; b2c[nt].b[3] = yfb;
        b2c[nt].b[4] = (__bf16)1.f; b2c[nt].b[5] = (__bf16)1.f;
        b2c[nt].b[6] = (__bf16)0.f; b2c[nt].b[7] = (__bf16)0.f;
    }

    const __bf16 one = (__bf16)1.f, zero = (__bf16)0.f;

    // ---- prologue: stage instance 0 into buffer 0 (336 float4 chunks)
    {
        const f32x4* src = (const f32x4*)(pk + (size_t)t0 * PKF);
        f32x4* dst = (f32x4*)plds[0];
        dst[tid] = src[tid];
        if (tid < 80) dst[256 + tid] = src[256 + tid];
    }
    __syncthreads();

    int cur = 0;
    for (int m = 0; m < M; ++m) {
        const int t = t0 + m;

        // issue next instance's staging loads BEFORE compute (latency hides)
        const bool have_next = (m + 1 < M);
        f32x4 s0, s1;
        if (have_next) {
            const f32x4* src = (const f32x4*)(pk + (size_t)(t + 1) * PKF);
            s0 = src[tid];
            if (tid < 80) s1 = src[256 + tid];
        }

        // fragment reads from LDS (imm-offset ds_read_b128, conflict-free)
        const short8* fp = (const short8*)plds[cur];
        short8 a00 = fp[lane];
        short8 a01 = fp[ 64 + lane];
        short8 a1b = fp[128 + lane];
        short8 a2r = fp[192 + lane];
        short8 ca  = fp[256 + lane];
        const float b2v = plds[cur][1280];   // uniform addr -> broadcast

        float oval = 0.f;
#pragma unroll
        for (int nt = 0; nt < 4; ++nt) {
            f32x4 acc0 = {0.f, 0.f, 0.f, 0.f};
            acc0 = __builtin_amdgcn_mfma_f32_16x16x32_bf16(ca,  b2c[nt].s,   acc0, 0, 0, 0);
            acc0 = __builtin_amdgcn_mfma_f32_16x16x32_bf16(a00, xb[nt][0].s, acc0, 0, 0, 0);
            acc0 = __builtin_amdgcn_mfma_f32_16x16x32_bf16(a01, xb[nt][1].s, acc0, 0, 0, 0);

            BF8 h0;
#pragma unroll
            for (int j = 0; j < 4; ++j) h0.b[j] = (__bf16)fmaxf(acc0[j], 0.f);
            h0.b[4] = one; h0.b[5] = one; h0.b[6] = zero; h0.b[7] = zero;

            f32x4 acc1 = {0.f, 0.f, 0.f, 0.f};
            acc1 = __builtin_amdgcn_mfma_f32_16x16x32_bf16(a1b, h0.s, acc1, 0, 0, 0);

            BF8 h1;
#pragma unroll
            for (int j = 0; j < 4; ++j) h1.b[j] = (__bf16)fmaxf(acc1[j], 0.f);
            h1.b[4] = zero; h1.b[5] = zero; h1.b[6] = zero; h1.b[7] = zero;

            f32x4 acc2 = {0.f, 0.f, 0.f, 0.f};
            acc2 = __builtin_amdgcn_mfma_f32_16x16x32_bf16(a2r, h1.s, acc2, 0, 0, 0);

            if (nt == g) oval = acc2[0] + b2v;   // lane's own tile, no shuffle
        }
        out[(size_t)t * HWSZ + pxw + lane] = oval;

        // write staged regs into the other buffer; barrier publishes it.
        // safety: writes target cur^1, whose last readers finished before
        // the barrier that published cur.
        if (have_next) {
            f32x4* dst = (f32x4*)plds[cur ^ 1];
            dst[tid] = s0;
            if (tid < 80) dst[256 + tid] = s1;
        }
        __syncthreads();
        cur ^= 1;
    }
}

// ---- fallback (no workspace): round-2-style kernel, params from global
__global__ __launch_bounds__(256) void mask_head_mfma_nows(
    const float* __restrict__ x,
    const float* __restrict__ params,
    const int*   __restrict__ num_ins,
    float*       __restrict__ out,
    int N, int T)
{
    const int tid  = threadIdx.x;
    const int wave = tid >> 6;
    const int lane = tid & 63;
    const int col  = lane & 15;
    const int g    = lane >> 4;
    const int n    = blockIdx.y;
    const int pxw  = blockIdx.x * 256 + wave * 64;

    int t0 = 0;
    for (int j = 0; j < n; ++j) t0 += num_ins[j];
    int t1 = t0 + num_ins[n];
    if (n == N - 1) t1 = T;
    if (t1 > T) t1 = T;

    BF8 xb[4][2];
    const float* xbase = x + (size_t)n * CIN * HWSZ + pxw + col;
#pragma unroll
    for (int nt = 0; nt < 4; ++nt)
#pragma unroll
        for (int c = 0; c < 2; ++c)
#pragma unroll
            for (int j = 0; j < 8; ++j)
                xb[nt][c].b[j] = (__bf16)xbase[(size_t)(c * 32 + g * 8 + j) * HWSZ + nt * 16];

    float xf[4], yf[4];
#pragma unroll
    for (int nt = 0; nt < 4; ++nt) {
        const int pix = pxw + nt * 16 + col;
        xf[nt] = (float)(pix & (WW - 1));
        yf[nt] = (float)(pix >> 8);
    }

    for (int t = t0; t < t1; ++t) {
        const float* pw = params + (size_t)t * PP;
        BF8 a00, a01, a1;
#pragma unroll
        for (int j = 0; j < 8; ++j) {
            a00.b[j] = (__bf16)pw[col * 66 + 2 +      g * 8 + j];
            a01.b[j] = (__bf16)pw[col * 66 + 2 + 32 + g * 8 + j];
        }
#pragma unroll
        for (int j = 0; j < 4; ++j) {
            a1.b[j]     = (__bf16)pw[1056 + col * 16 + g * 4 + j];
            a1.b[4 + j] = (__bf16)0.f;
        }
        float wxv[4], wyv[4], b0v[4], b1v[4], w2v[4];
#pragma unroll
        for (int j = 0; j < 4; ++j) {
            const int r = g * 4 + j;
            wxv[j] = pw[r * 66 + 0];
            wyv[j] = pw[r * 66 + 1];
            b0v[j] = pw[1328 + r];
            b1v[j] = pw[1344 + r];
            w2v[j] = pw[1312 + r];
        }
        const float b2v = pw[1360] - MASK_BIAS_SHIFT;

        f32x4 acc0[4];
#pragma unroll
        for (int nt = 0; nt < 4; ++nt) {
            f32x4 a = {0.f, 0.f, 0.f, 0.f};
            a = __builtin_amdgcn_mfma_f32_16x16x32_bf16(a00.s, xb[nt][0].s, a, 0, 0, 0);
            a = __builtin_amdgcn_mfma_f32_16x16x32_bf16(a01.s, xb[nt][1].s, a, 0, 0, 0);
            acc0[nt] = a;
        }
        BF8 h0[4];
#pragma unroll
        for (int nt = 0; nt < 4; ++nt)
#pragma unroll
            for (int j = 0; j < 4; ++j) {
                float v = acc0[nt][j] + b0v[j];
                v = fmaf(wxv[j], xf[nt], v);
                v = fmaf(wyv[j], yf[nt], v);
                v = fmaxf(v, 0.f);
                h0[nt].b[j]     = (__bf16)v;
                h0[nt].b[4 + j] = (__bf16)0.f;
            }
        f32x4 acc1[4];
#pragma unroll
        for (int nt = 0; nt < 4; ++nt) {
            f32x4 a = {0.f, 0.f, 0.f, 0.f};
            acc1[nt] = __builtin_amdgcn_mfma_f32_16x16x32_bf16(a1.s, h0[nt].s, a, 0, 0, 0);
        }
        float oval = 0.f;
#pragma unroll
        for (int nt = 0; nt < 4; ++nt) {
            float sum = 0.f;
#pragma unroll
            for (int j = 0; j < 4; ++j) {
                const float h = fmaxf(acc1[nt][j] + b1v[j], 0.f);
                sum = fmaf(w2v[j], h, sum);
            }
            sum += __shfl_xor(sum, 16, 64);
            sum += __shfl_xor(sum, 32, 64);
            if (nt == g) oval = sum + b2v;
        }
        out[(size_t)t * HWSZ + pxw + lane] = oval;
    }
}

extern "C" void kernel_launch(void* const* d_in, const int* in_sizes, int n_in,
                              void* d_out, int out_size, void* d_ws, size_t ws_size,
                              hipStream_t stream) {
    const float* x      = (const float*)d_in[0];
    const float* params = (const float*)d_in[1];
    const int*   nins   = (const int*)d_in[2];
    float*       out    = (float*)d_out;

    const int N = in_sizes[2];            // images
    const int T = in_sizes[1] / PP;       // total instances (param rows)
    const size_t ws_needed = (size_t)T * PKF * sizeof(float);

    if (ws_size >= ws_needed) {
        float* pk = (float*)d_ws;
        prep_params<<<T, dim3(64), 0, stream>>>(params, pk);
        dim3 grid(HWSZ / 256, N);         // 160 x 4 = 640 blocks of 4 waves
        mask_head_v7<<<grid, dim3(256), 0, stream>>>(x, pk, nins, out, N, T);
    } else {
        dim3 grid(HWSZ / 256, N);
        mask_head_mfma_nows<<<grid, dim3(256), 0, stream>>>(x, params, nins, out, N, T);
    }
}

// Round 8
// 30.977 us; speedup vs baseline: 1.3574x; 1.0546x over previous
//
#include <hip/hip_runtime.h>

// DynamicMaskHead v8: all-MFMA (v5 math, verified absmax 0.046875) +
// 2-deep register ping-pong prefetch of per-instance param fragments.
// Wave = 64 px, loops instances m = s, s+2, ... (NSPLIT=2 across gridDim.z).
// While computing instance t, the 6 loads for instance t+NSPLIT are already
// in flight into the other Frag register set -> per-iteration load stall ~0.
// Per (instance, 16-px tile): 5 MFMAs:
//   acc0 = ca·coords + W0a·X + W0b·X ; h0=relu -> a1b MFMA (b1 channel)
//   -> h1=relu -> a2r MFMA (row-replicated w2) => lane keeps tile nt==g,
//   one 64-lane coalesced store per instance. Zero shuffles.

#define CIN  64
#define HH   160
#define WW   256
#define HWSZ (HH * WW)
#define PP   1361
#define MASK_BIAS_SHIFT 2.19f
#define PKF  1344              // floats per instance in packed buffer (5376 B)
#define NSPLIT 2               // instance split across gridDim.z

typedef short short8 __attribute__((ext_vector_type(8)));
typedef float f32x4  __attribute__((ext_vector_type(4)));

union BF8 { short8 s; __bf16 b[8]; };

__device__ inline __bf16 bhi(float v) { return (__bf16)v; }
__device__ inline __bf16 blo(float v) { return (__bf16)(v - (float)(__bf16)v); }

// packed float offsets per instance:
//   0: a00 (W0 x-ch 0..31)   256: a01 (x-ch 32..63)   512: a1b (W1 + b1 ch)
//   768: a2r (replicated w2) 1024: ca (coord/b0 ch)   1280: b2 (scalar)

__global__ __launch_bounds__(64) void prep_params(
    const float* __restrict__ params, float* __restrict__ pk)
{
    const int t    = blockIdx.x;
    const int lane = threadIdx.x;
    const int col  = lane & 15;
    const int g    = lane >> 4;
    const float* pw = params + (size_t)t * PP;
    float* dst = pk + (size_t)t * PKF;

    const __bf16 z = (__bf16)0.f;

    BF8 a00, a01;
#pragma unroll
    for (int j = 0; j < 8; ++j) {
        a00.b[j] = (__bf16)pw[col * 66 + 2 +      g * 8 + j];
        a01.b[j] = (__bf16)pw[col * 66 + 2 + 32 + g * 8 + j];
    }

    BF8 a1b;                                   // W1 (k=0..15) + b1 bias channel
#pragma unroll
    for (int j = 0; j < 4; ++j)
        a1b.b[j] = (__bf16)pw[1056 + col * 16 + g * 4 + j];
    {
        const float b1 = pw[1344 + col];
        a1b.b[4] = (g == 0) ? bhi(b1) : z;
        a1b.b[5] = (g == 0) ? blo(b1) : z;
        a1b.b[6] = z;  a1b.b[7] = z;
    }

    BF8 a2r;                                   // w2 replicated across rows
#pragma unroll
    for (int j = 0; j < 4; ++j) a2r.b[j] = (__bf16)pw[1312 + g * 4 + j];
    a2r.b[4] = z; a2r.b[5] = z; a2r.b[6] = z; a2r.b[7] = z;

    BF8 ca;   // [wx_hi,wx_lo,wy_hi,wy_lo,b0_hi,b0_lo,0,0] on g==0 lanes
    {
        const float wx = pw[col * 66 + 0];
        const float wy = pw[col * 66 + 1];
        const float b0 = pw[1328 + col];
        ca.b[0] = (g == 0) ? bhi(wx) : z;
        ca.b[1] = (g == 0) ? blo(wx) : z;
        ca.b[2] = (g == 0) ? bhi(wy) : z;
        ca.b[3] = (g == 0) ? blo(wy) : z;
        ca.b[4] = (g == 0) ? bhi(b0) : z;
        ca.b[5] = (g == 0) ? blo(b0) : z;
        ca.b[6] = z; ca.b[7] = z;
    }

    ((short8*)(dst       ))[lane] = a00.s;
    ((short8*)(dst +  256))[lane] = a01.s;
    ((short8*)(dst +  512))[lane] = a1b.s;
    ((short8*)(dst +  768))[lane] = a2r.s;
    ((short8*)(dst + 1024))[lane] = ca.s;
    if (lane == 0) dst[1280] = pw[1360] - MASK_BIAS_SHIFT;
}

struct Frag {
    short8 a00, a01, a1b, a2r, ca;
    float  b2;
};

__device__ __forceinline__ void frag_load(const float* __restrict__ pt,
                                          int lane, Frag& f)
{
    f.a00 = ((const short8*)(pt       ))[lane];
    f.a01 = ((const short8*)(pt +  256))[lane];
    f.a1b = ((const short8*)(pt +  512))[lane];
    f.a2r = ((const short8*)(pt +  768))[lane];
    f.ca  = ((const short8*)(pt + 1024))[lane];
    f.b2  = pt[1280];
}

__device__ __forceinline__ void frag_compute(
    const Frag& f, const BF8 (&xb)[4][2], const BF8 (&b2c)[4],
    int g, float* __restrict__ outp)
{
    const __bf16 one = (__bf16)1.f, zero = (__bf16)0.f;
    float oval = 0.f;
#pragma unroll
    for (int nt = 0; nt < 4; ++nt) {
        f32x4 acc0 = {0.f, 0.f, 0.f, 0.f};
        acc0 = __builtin_amdgcn_mfma_f32_16x16x32_bf16(f.ca,  b2c[nt].s,   acc0, 0, 0, 0);
        acc0 = __builtin_amdgcn_mfma_f32_16x16x32_bf16(f.a00, xb[nt][0].s, acc0, 0, 0, 0);
        acc0 = __builtin_amdgcn_mfma_f32_16x16x32_bf16(f.a01, xb[nt][1].s, acc0, 0, 0, 0);

        BF8 h0;
#pragma unroll
        for (int j = 0; j < 4; ++j) h0.b[j] = (__bf16)fmaxf(acc0[j], 0.f);
        h0.b[4] = one; h0.b[5] = one; h0.b[6] = zero; h0.b[7] = zero;

        f32x4 acc1 = {0.f, 0.f, 0.f, 0.f};
        acc1 = __builtin_amdgcn_mfma_f32_16x16x32_bf16(f.a1b, h0.s, acc1, 0, 0, 0);

        BF8 h1;
#pragma unroll
        for (int j = 0; j < 4; ++j) h1.b[j] = (__bf16)fmaxf(acc1[j], 0.f);
        h1.b[4] = zero; h1.b[5] = zero; h1.b[6] = zero; h1.b[7] = zero;

        f32x4 acc2 = {0.f, 0.f, 0.f, 0.f};
        acc2 = __builtin_amdgcn_mfma_f32_16x16x32_bf16(f.a2r, h1.s, acc2, 0, 0, 0);

        if (nt == g) oval = acc2[0] + f.b2;   // lane's own tile, no shuffle
    }
    *outp = oval;
}

__global__ __launch_bounds__(256, 4) void mask_head_v8(
    const float* __restrict__ x,
    const float* __restrict__ pk,
    const int*   __restrict__ num_ins,
    float*       __restrict__ out,
    int N, int T)
{
    const int tid  = threadIdx.x;
    const int wave = tid >> 6;
    const int lane = tid & 63;
    const int col  = lane & 15;
    const int g    = lane >> 4;
    const int n    = blockIdx.y;
    const int s    = blockIdx.z;
    const int pxw  = blockIdx.x * 256 + wave * 64;

    // instance range for this image (repeat-pad on last image)
    int t0 = 0;
    for (int j = 0; j < n; ++j) t0 += num_ins[j];
    int t1 = t0 + num_ins[n];
    if (n == N - 1) t1 = T;
    if (t1 > T) t1 = T;
    t0 = __builtin_amdgcn_readfirstlane(t0);
    t1 = __builtin_amdgcn_readfirstlane(t1);

    int t = t0 + s;
    if (t >= t1) return;

    // first instance's fragments: issue loads before the x preamble so the
    // latency overlaps the 64 x loads + conversions below
    Frag fA, fB;
    frag_load(pk + (size_t)t * PKF, lane, fA);

    // x fragments: 64 px x 64 ch (32 VGPR), loaded once, reused by all inst
    BF8 xb[4][2];
    const float* xbase = x + (size_t)n * CIN * HWSZ + pxw + col;
#pragma unroll
    for (int nt = 0; nt < 4; ++nt)
#pragma unroll
        for (int c = 0; c < 2; ++c)
#pragma unroll
            for (int j = 0; j < 8; ++j) {
                const int ch = c * 32 + g * 8 + j;
                xb[nt][c].b[j] = (__bf16)xbase[(size_t)ch * HWSZ + nt * 16];
            }

    // coordinate B-fragments (instance-independent): [xf,xf,yf,yf,1,1,0,0]
    BF8 b2c[4];
#pragma unroll
    for (int nt = 0; nt < 4; ++nt) {
        const int px = pxw + nt * 16 + col;
        const __bf16 xfb = (__bf16)(float)(px & (WW - 1));
        const __bf16 yfb = (__bf16)(float)(px >> 8);
        b2c[nt].b[0] = xfb; b2c[nt].b[1] = xfb;
        b2c[nt].b[2] = yfb; b2c[nt].b[3] = yfb;
        b2c[nt].b[4] = (__bf16)1.f; b2c[nt].b[5] = (__bf16)1.f;
        b2c[nt].b[6] = (__bf16)0.f; b2c[nt].b[7] = (__bf16)0.f;
    }

    float* const obase = out + pxw + lane;

    // ---- 2-deep ping-pong pipeline over instances (stride NSPLIT)
    for (;;) {
        const int tB = t + NSPLIT;
        if (tB < t1) frag_load(pk + (size_t)tB * PKF, lane, fB);
        frag_compute(fA, xb, b2c, g, obase + (size_t)t * HWSZ);
        if (tB >= t1) break;

        const int tA = tB + NSPLIT;
        if (tA < t1) frag_load(pk + (size_t)tA * PKF, lane, fA);
        frag_compute(fB, xb, b2c, g, obase + (size_t)tB * HWSZ);
        if (tA >= t1) break;
        t = tA;
    }
}

// ---- fallback (no workspace): round-2-style kernel, params from global
__global__ __launch_bounds__(256) void mask_head_mfma_nows(
    const float* __restrict__ x,
    const float* __restrict__ params,
    const int*   __restrict__ num_ins,
    float*       __restrict__ out,
    int N, int T)
{
    const int tid  = threadIdx.x;
    const int wave = tid >> 6;
    const int lane = tid & 63;
    const int col  = lane & 15;
    const int g    = lane >> 4;
    const int n    = blockIdx.y;
    const int pxw  = blockIdx.x * 256 + wave * 64;

    int t0 = 0;
    for (int j = 0; j < n; ++j) t0 += num_ins[j];
    int t1 = t0 + num_ins[n];
    if (n == N - 1) t1 = T;
    if (t1 > T) t1 = T;

    BF8 xb[4][2];
    const float* xbase = x + (size_t)n * CIN * HWSZ + pxw + col;
#pragma unroll
    for (int nt = 0; nt < 4; ++nt)
#pragma unroll
        for (int c = 0; c < 2; ++c)
#pragma unroll
            for (int j = 0; j < 8; ++j)
                xb[nt][c].b[j] = (__bf16)xbase[(size_t)(c * 32 + g * 8 + j) * HWSZ + nt * 16];

    float xf[4], yf[4];
#pragma unroll
    for (int nt = 0; nt < 4; ++nt) {
        const int pix = pxw + nt * 16 + col;
        xf[nt] = (float)(pix & (WW - 1));
        yf[nt] = (float)(pix >> 8);
    }

    for (int t = t0; t < t1; ++t) {
        const float* pw = params + (size_t)t * PP;
        BF8 a00, a01, a1;
#pragma unroll
        for (int j = 0; j < 8; ++j) {
            a00.b[j] = (__bf16)pw[col * 66 + 2 +      g * 8 + j];
            a01.b[j] = (__bf16)pw[col * 66 + 2 + 32 + g * 8 + j];
        }
#pragma unroll
        for (int j = 0; j < 4; ++j) {
            a1.b[j]     = (__bf16)pw[1056 + col * 16 + g * 4 + j];
            a1.b[4 + j] = (__bf16)0.f;
        }
        float wxv[4], wyv[4], b0v[4], b1v[4], w2v[4];
#pragma unroll
        for (int j = 0; j < 4; ++j) {
            const int r = g * 4 + j;
            wxv[j] = pw[r * 66 + 0];
            wyv[j] = pw[r * 66 + 1];
            b0v[j] = pw[1328 + r];
            b1v[j] = pw[1344 + r];
            w2v[j] = pw[1312 + r];
        }
        const float b2v = pw[1360] - MASK_BIAS_SHIFT;

        f32x4 acc0[4];
#pragma unroll
        for (int nt = 0; nt < 4; ++nt) {
            f32x4 a = {0.f, 0.f, 0.f, 0.f};
            a = __builtin_amdgcn_mfma_f32_16x16x32_bf16(a00.s, xb[nt][0].s, a, 0, 0, 0);
            a = __builtin_amdgcn_mfma_f32_16x16x32_bf16(a01.s, xb[nt][1].s, a, 0, 0, 0);
            acc0[nt] = a;
        }
        BF8 h0[4];
#pragma unroll
        for (int nt = 0; nt < 4; ++nt)
#pragma unroll
            for (int j = 0; j < 4; ++j) {
                float v = acc0[nt][j] + b0v[j];
                v = fmaf(wxv[j], xf[nt], v);
                v = fmaf(wyv[j], yf[nt], v);
                v = fmaxf(v, 0.f);
                h0[nt].b[j]     = (__bf16)v;
                h0[nt].b[4 + j] = (__bf16)0.f;
            }
        f32x4 acc1[4];
#pragma unroll
        for (int nt = 0; nt < 4; ++nt) {
            f32x4 a = {0.f, 0.f, 0.f, 0.f};
            acc1[nt] = __builtin_amdgcn_mfma_f32_16x16x32_bf16(a1.s, h0[nt].s, a, 0, 0, 0);
        }
        float oval = 0.f;
#pragma unroll
        for (int nt = 0; nt < 4; ++nt) {
            float sum = 0.f;
#pragma unroll
            for (int j = 0; j < 4; ++j) {
                const float h = fmaxf(acc1[nt][j] + b1v[j], 0.f);
                sum = fmaf(w2v[j], h, sum);
            }
            sum += __shfl_xor(sum, 16, 64);
            sum += __shfl_xor(sum, 32, 64);
            if (nt == g) oval = sum + b2v;
        }
        out[(size_t)t * HWSZ + pxw + lane] = oval;
    }
}

extern "C" void kernel_launch(void* const* d_in, const int* in_sizes, int n_in,
                              void* d_out, int out_size, void* d_ws, size_t ws_size,
                              hipStream_t stream) {
    const float* x      = (const float*)d_in[0];
    const float* params = (const float*)d_in[1];
    const int*   nins   = (const int*)d_in[2];
    float*       out    = (float*)d_out;

    const int N = in_sizes[2];            // images
    const int T = in_sizes[1] / PP;       // total instances (param rows)
    const size_t ws_needed = (size_t)T * PKF * sizeof(float);

    if (ws_size >= ws_needed) {
        float* pk = (float*)d_ws;
        prep_params<<<T, dim3(64), 0, stream>>>(params, pk);
        dim3 grid(HWSZ / 256, N, NSPLIT);
        mask_head_v8<<<grid, dim3(256), 0, stream>>>(x, pk, nins, out, N, T);
    } else {
        dim3 grid(HWSZ / 256, N);
        mask_head_mfma_nows<<<grid, dim3(256), 0, stream>>>(x, params, nins, out, N, T);
    }
}